// Round 4
// baseline (620.464 us; speedup 1.0000x reference)
//
#include <hip/hip_runtime.h>
#include <hip/hip_bf16.h>

// TransformerBlock: B=2, S=2048, D=1024, H=16, hd=64, C=1024
// External tensors are FLOAT32 (per reference dtypes). Internal compute uses
// bf16 MFMA (f32 accumulate); comparison threshold is bf16-scale.
// Workspace peak: 48 MB + 48 KB. d_out (f32, 16.8 MB) doubles as bf16 scratch
// for h / ob / h2 (8.4 MB each, lifetimes disjoint in stream order).

typedef unsigned short u16;
typedef unsigned int   u32;
typedef __bf16 bf16x8 __attribute__((ext_vector_type(8)));
typedef float  f32x4  __attribute__((ext_vector_type(4)));

#define MFMA_BF16(a, b, c) __builtin_amdgcn_mfma_f32_16x16x32_bf16((a), (b), (c), 0, 0, 0)

__device__ __forceinline__ float b2f(u16 u) {
    union { u32 i; float f; } v; v.i = ((u32)u) << 16; return v.f;
}
__device__ __forceinline__ u16 f2b(float f) {
    union { u32 i; float f; } v; v.f = f;
    u32 i = v.i;
    return (u16)((i + 0x7FFFu + ((i >> 16) & 1u)) >> 16);  // RNE
}
__device__ __forceinline__ float finz(float v) {
    return __builtin_isfinite(v) ? v : 0.0f;
}

// ---------------------------------------------------------------------------
// mods = c @ ada_w.T + ada_b : (2, 6144), K=1024. One wave per column. f32 in.
// ---------------------------------------------------------------------------
__global__ __launch_bounds__(64) void mods_kernel(
    const float* __restrict__ c, const float* __restrict__ ada_w,
    const float* __restrict__ ada_b, float* __restrict__ mods)
{
    const int n = blockIdx.x;
    const int lane = threadIdx.x;
    const float* wr = ada_w + (size_t)n * 1024;
    float a0 = 0.f, a1 = 0.f;
    for (int k = lane; k < 1024; k += 64) {
        float w = wr[k];
        a0 += w * c[k];
        a1 += w * c[1024 + k];
    }
    for (int o = 32; o > 0; o >>= 1) {
        a0 += __shfl_down(a0, o, 64);
        a1 += __shfl_down(a1, o, 64);
    }
    if (lane == 0) {
        float bb = ada_b[n];
        mods[n]        = a0 + bb;
        mods[6144 + n] = a1 + bb;
    }
}

// ---------------------------------------------------------------------------
// LayerNorm + adaLN modulation. f32 input, bf16 output. Block per row.
// mods per batch: [shift_msa|scale_msa|gate_msa|shift_mlp|scale_mlp|gate_mlp]
// ---------------------------------------------------------------------------
__global__ __launch_bounds__(256) void ln_mod_kernel(
    const float* __restrict__ xf, const float* __restrict__ w,
    const float* __restrict__ mods,
    int scale_off, int shift_off, u16* __restrict__ out)
{
    const int row = blockIdx.x;          // b*2048 + s
    const int b   = row >> 11;
    const int tid = threadIdx.x;
    const size_t base = (size_t)row * 1024 + tid * 4;
    float4 t = *(const float4*)(xf + base);
    float v[4] = {t.x, t.y, t.z, t.w};
    float s  = v[0] + v[1] + v[2] + v[3];
    float sq = v[0]*v[0] + v[1]*v[1] + v[2]*v[2] + v[3]*v[3];
    __shared__ float rs[256], rq[256];
    rs[tid] = s; rq[tid] = sq;
    __syncthreads();
    for (int o = 128; o > 0; o >>= 1) {
        if (tid < o) { rs[tid] += rs[tid + o]; rq[tid] += rq[tid + o]; }
        __syncthreads();
    }
    const float mean = rs[0] * (1.0f / 1024.0f);
    const float var  = rq[0] * (1.0f / 1024.0f) - mean * mean;
    const float inv  = rsqrtf(fmaxf(var, 0.f) + 1e-5f);
    for (int i = 0; i < 4; ++i) {
        int cidx = tid * 4 + i;
        float y = (v[i] - mean) * inv * w[cidx];
        y = y * (1.0f + mods[b * 6144 + scale_off + cidx]) + mods[b * 6144 + shift_off + cidx];
        out[base + i] = f2b(y);
    }
}

// ---------------------------------------------------------------------------
// MFMA GEMM: C[M,N] = A[M,K] @ W[N,K]^T. A is internal bf16; W is external
// f32, converted to bf16 during LDS staging. 64x64 tile, BK=32, 4 waves (2x2).
// MODE 1: +bias(f32), exact GELU, bf16 out (fc1)
// MODE 2: gate_msa*val + resid(f32 x), f32 out (out-proj -> x2)
// MODE 3: +bias(f32), gate_mlp*val + resid(f32 x2), f32 out -> d_out (sanitized)
// MODE 4: scatter q (aux1), k (aux2) as (b,h,s,d) and v^T (out_bf) (b,h,d,s)
// ---------------------------------------------------------------------------
template<int MODE>
__global__ __launch_bounds__(256) void gemm_kernel(
    const u16* __restrict__ A, const float* __restrict__ W,
    int M, int N, int K,
    const float* __restrict__ mods,
    const float* __restrict__ bias,
    const float* __restrict__ resid,
    float* __restrict__ out_f,
    u16* __restrict__ out_bf,
    u16* __restrict__ aux1,
    u16* __restrict__ aux2)
{
    __shared__ u16 As[64][40];
    __shared__ u16 Bs[64][40];
    const int tid  = threadIdx.x;
    const int wave = tid >> 6, lane = tid & 63;
    const int quad = lane >> 4, l15 = lane & 15;
    const int wi = wave >> 1, wj = wave & 1;
    const int m0 = blockIdx.y * 64, n0 = blockIdx.x * 64;

    f32x4 acc[2][2] = {{{0.f,0.f,0.f,0.f},{0.f,0.f,0.f,0.f}},
                       {{0.f,0.f,0.f,0.f},{0.f,0.f,0.f,0.f}}};

    const int lrow = tid >> 2;           // 0..63
    const int lkg  = (tid & 3) * 8;      // 0,8,16,24
    const u16*  Ag = A + (size_t)(m0 + lrow) * K + lkg;
    const float* Wg = W + (size_t)(n0 + lrow) * K + lkg;

    for (int k0 = 0; k0 < K; k0 += 32) {
        __syncthreads();
        *(float4*)(&As[lrow][lkg]) = *(const float4*)(Ag + k0);
        float4 w0 = *(const float4*)(Wg + k0);
        float4 w1 = *(const float4*)(Wg + k0 + 4);
        union { u16 s[8]; float4 v; } wp;
        wp.s[0] = f2b(w0.x); wp.s[1] = f2b(w0.y);
        wp.s[2] = f2b(w0.z); wp.s[3] = f2b(w0.w);
        wp.s[4] = f2b(w1.x); wp.s[5] = f2b(w1.y);
        wp.s[6] = f2b(w1.z); wp.s[7] = f2b(w1.w);
        *(float4*)(&Bs[lrow][lkg]) = wp.v;
        __syncthreads();
        bf16x8 a0 = *(const bf16x8*)(&As[wi * 32 + l15][quad * 8]);
        bf16x8 a1 = *(const bf16x8*)(&As[wi * 32 + 16 + l15][quad * 8]);
        bf16x8 b0 = *(const bf16x8*)(&Bs[wj * 32 + l15][quad * 8]);
        bf16x8 b1 = *(const bf16x8*)(&Bs[wj * 32 + 16 + l15][quad * 8]);
        acc[0][0] = MFMA_BF16(a0, b0, acc[0][0]);
        acc[0][1] = MFMA_BF16(a0, b1, acc[0][1]);
        acc[1][0] = MFMA_BF16(a1, b0, acc[1][0]);
        acc[1][1] = MFMA_BF16(a1, b1, acc[1][1]);
    }

    #pragma unroll
    for (int ti = 0; ti < 2; ++ti) {
        #pragma unroll
        for (int tj = 0; tj < 2; ++tj) {
            const int cidx  = n0 + wj * 32 + tj * 16 + l15;
            const int rbase = m0 + wi * 32 + ti * 16 + quad * 4;
            #pragma unroll
            for (int reg = 0; reg < 4; ++reg) {
                const int r = rbase + reg;
                float v = acc[ti][tj][reg];
                if (MODE == 1) {
                    float u = v + bias[cidx];
                    float g = 0.5f * u * (1.0f + erff(u * 0.70710678118654752f));
                    out_bf[(size_t)r * N + cidx] = f2b(g);
                } else if (MODE == 2) {
                    int bb = r >> 11;
                    float gate = mods[bb * 6144 + 2048 + cidx];  // gate_msa
                    out_f[(size_t)r * N + cidx] = gate * v + resid[(size_t)r * N + cidx];
                } else if (MODE == 3) {
                    int bb = r >> 11;
                    float u = v + bias[cidx];
                    float gate = mods[bb * 6144 + 5120 + cidx];  // gate_mlp
                    out_f[(size_t)r * N + cidx] = finz(gate * u + resid[(size_t)r * N + cidx]);
                } else {  // MODE 4: qkv scatter
                    int w  = cidx >> 10;
                    int rem = cidx & 1023;
                    int hh = rem >> 6, d = rem & 63;
                    int bb = r >> 11, s = r & 2047;
                    int bh = bb * 16 + hh;
                    u16 val = f2b(v);
                    if (w == 0)      aux1[((size_t)bh * 2048 + s) * 64 + d] = val;
                    else if (w == 1) aux2[((size_t)bh * 2048 + s) * 64 + d] = val;
                    else             out_bf[((size_t)bh * 64 + d) * 2048 + s] = val;
                }
            }
        }
    }
}

// ---------------------------------------------------------------------------
// In-place RoPE on q and k, layout (b,h,s,d). Thread owns pair (d2, d2+32).
// q additionally scaled by hd^-0.5. cos/sin are f32.
// ---------------------------------------------------------------------------
__global__ __launch_bounds__(256) void rope_qk_kernel(
    u16* __restrict__ qs, u16* __restrict__ ks,
    const float* __restrict__ rcos, const float* __restrict__ rsin)
{
    int t  = blockIdx.x * 256 + threadIdx.x;
    int d2 = t & 31;  int t1 = t >> 5;
    int s  = t1 & 2047; int t2 = t1 >> 11;
    int bh = t2 & 31;   int which = t2 >> 5;
    u16* buf = which ? ks : qs;
    size_t base = ((size_t)bh * 2048 + s) * 64;
    float xa = b2f(buf[base + d2]);
    float xb = b2f(buf[base + d2 + 32]);
    float ca = rcos[s * 64 + d2];
    float cb = rcos[s * 64 + d2 + 32];
    float sa = rsin[s * 64 + d2];
    float sb = rsin[s * 64 + d2 + 32];
    float ra = xa * ca - xb * sa;
    float rb = xb * cb + xa * sb;
    if (!which) { ra *= 0.125f; rb *= 0.125f; }
    buf[base + d2]      = f2b(ra);
    buf[base + d2 + 32] = f2b(rb);
}

// In-place RoPE on v^T, layout (b,h,d,s).
__global__ __launch_bounds__(256) void rope_v_kernel(
    u16* __restrict__ vT,
    const float* __restrict__ rcos, const float* __restrict__ rsin)
{
    int t  = blockIdx.x * 256 + threadIdx.x;
    int s  = t & 2047; int t1 = t >> 11;
    int d2 = t1 & 31;  int bh = t1 >> 5;
    size_t ia = ((size_t)bh * 64 + d2) * 2048 + s;
    size_t ib = ((size_t)bh * 64 + d2 + 32) * 2048 + s;
    float xa = b2f(vT[ia]);
    float xb = b2f(vT[ib]);
    float ca = rcos[s * 64 + d2];
    float cb = rcos[s * 64 + d2 + 32];
    float sa = rsin[s * 64 + d2];
    float sb = rsin[s * 64 + d2 + 32];
    vT[ia] = f2b(xa * ca - xb * sa);
    vT[ib] = f2b(xb * cb + xa * sb);
}

// ---------------------------------------------------------------------------
// Flash attention, MFMA 16x16x32. Block = (b,h, 64-query tile), 4 waves of
// 16 queries. Online softmax in C-layout; P via LDS to A-layout.
// ---------------------------------------------------------------------------
__global__ __launch_bounds__(256) void attn_kernel(
    const u16* __restrict__ Q, const u16* __restrict__ Kg,
    const u16* __restrict__ Vg, u16* __restrict__ O)
{
    __shared__ u16 Ks[64][72];
    __shared__ u16 Vs[64][72];       // V^T tile: [d][key]
    __shared__ u16 Ps[4][16][72];
    const int tid  = threadIdx.x;
    const int wave = tid >> 6, lane = tid & 63;
    const int quad = lane >> 4, l15 = lane & 15;
    const int qtile = blockIdx.x & 31, bh = blockIdx.x >> 5;

    const u16* Qh = Q  + ((size_t)bh * 2048 + qtile * 64) * 64;
    const u16* Kh = Kg + (size_t)bh * 2048 * 64;
    const u16* Vh = Vg + (size_t)bh * 64 * 2048;

    bf16x8 aq0 = *(const bf16x8*)(Qh + (size_t)(wave * 16 + l15) * 64 + quad * 8);
    bf16x8 aq1 = *(const bf16x8*)(Qh + (size_t)(wave * 16 + l15) * 64 + 32 + quad * 8);

    f32x4 acc_o[4] = {{0.f,0.f,0.f,0.f},{0.f,0.f,0.f,0.f},
                      {0.f,0.f,0.f,0.f},{0.f,0.f,0.f,0.f}};
    float m_r[4], l_r[4];
    #pragma unroll
    for (int r = 0; r < 4; ++r) { m_r[r] = -1e30f; l_r[r] = 0.f; }

    const int srow = tid >> 2;           // 0..63
    const int sseg = (tid & 3) * 16;     // 0,16,32,48

    for (int kbase = 0; kbase < 2048; kbase += 64) {
        __syncthreads();
        *(float4*)(&Ks[srow][sseg])     = *(const float4*)(Kh + (size_t)(kbase + srow) * 64 + sseg);
        *(float4*)(&Ks[srow][sseg + 8]) = *(const float4*)(Kh + (size_t)(kbase + srow) * 64 + sseg + 8);
        *(float4*)(&Vs[srow][sseg])     = *(const float4*)(Vh + (size_t)srow * 2048 + kbase + sseg);
        *(float4*)(&Vs[srow][sseg + 8]) = *(const float4*)(Vh + (size_t)srow * 2048 + kbase + sseg + 8);
        __syncthreads();

        f32x4 sc[4] = {{0.f,0.f,0.f,0.f},{0.f,0.f,0.f,0.f},
                       {0.f,0.f,0.f,0.f},{0.f,0.f,0.f,0.f}};
        #pragma unroll
        for (int kt = 0; kt < 4; ++kt) {
            bf16x8 bk0 = *(const bf16x8*)(&Ks[kt * 16 + l15][quad * 8]);
            bf16x8 bk1 = *(const bf16x8*)(&Ks[kt * 16 + l15][32 + quad * 8]);
            sc[kt] = MFMA_BF16(aq0, bk0, sc[kt]);
            sc[kt] = MFMA_BF16(aq1, bk1, sc[kt]);
        }

        #pragma unroll
        for (int reg = 0; reg < 4; ++reg) {
            float mx = fmaxf(fmaxf(sc[0][reg], sc[1][reg]), fmaxf(sc[2][reg], sc[3][reg]));
            mx = fmaxf(mx, __shfl_xor(mx, 1, 64));
            mx = fmaxf(mx, __shfl_xor(mx, 2, 64));
            mx = fmaxf(mx, __shfl_xor(mx, 4, 64));
            mx = fmaxf(mx, __shfl_xor(mx, 8, 64));
            float mnew  = fmaxf(m_r[reg], mx);
            float alpha = __expf(fminf(m_r[reg] - mnew, 0.f));
            float rs = 0.f;
            #pragma unroll
            for (int kt = 0; kt < 4; ++kt) {
                float p = __expf(fminf(sc[kt][reg] - mnew, 0.f));
                sc[kt][reg] = p; rs += p;
            }
            rs += __shfl_xor(rs, 1, 64);
            rs += __shfl_xor(rs, 2, 64);
            rs += __shfl_xor(rs, 4, 64);
            rs += __shfl_xor(rs, 8, 64);
            l_r[reg] = l_r[reg] * alpha + rs;
            m_r[reg] = mnew;
            #pragma unroll
            for (int dt = 0; dt < 4; ++dt) acc_o[dt][reg] *= alpha;
        }

        #pragma unroll
        for (int kt = 0; kt < 4; ++kt)
            #pragma unroll
            for (int reg = 0; reg < 4; ++reg)
                Ps[wave][quad * 4 + reg][kt * 16 + l15] = f2b(sc[kt][reg]);
        __syncthreads();

        bf16x8 ap0 = *(const bf16x8*)(&Ps[wave][l15][quad * 8]);
        bf16x8 ap1 = *(const bf16x8*)(&Ps[wave][l15][32 + quad * 8]);
        #pragma unroll
        for (int dt = 0; dt < 4; ++dt) {
            bf16x8 bv0 = *(const bf16x8*)(&Vs[dt * 16 + l15][quad * 8]);
            bf16x8 bv1 = *(const bf16x8*)(&Vs[dt * 16 + l15][32 + quad * 8]);
            acc_o[dt] = MFMA_BF16(ap0, bv0, acc_o[dt]);
            acc_o[dt] = MFMA_BF16(ap1, bv1, acc_o[dt]);
        }
    }

    const int b = bh >> 4, hh = bh & 15;
    const int q0 = qtile * 64 + wave * 16 + quad * 4;
    #pragma unroll
    for (int dt = 0; dt < 4; ++dt)
        #pragma unroll
        for (int reg = 0; reg < 4; ++reg) {
            float v = acc_o[dt][reg] / l_r[reg];
            O[((size_t)(b * 2048 + q0 + reg)) * 1024 + hh * 64 + dt * 16 + l15] = f2b(v);
        }
}

// ---------------------------------------------------------------------------
extern "C" void kernel_launch(void* const* d_in, const int* in_sizes, int n_in,
                              void* d_out, int out_size, void* d_ws, size_t ws_size,
                              hipStream_t stream)
{
    const float* x     = (const float*)d_in[0];
    const float* rcos  = (const float*)d_in[1];
    const float* rsin  = (const float*)d_in[2];
    const float* c     = (const float*)d_in[3];
    const float* n1w   = (const float*)d_in[4];
    const float* qkvw  = (const float*)d_in[5];
    const float* outw  = (const float*)d_in[6];
    const float* n2w   = (const float*)d_in[7];
    const float* fc1w  = (const float*)d_in[8];
    const float* fc1b  = (const float*)d_in[9];
    const float* fc2w  = (const float*)d_in[10];
    const float* fc2b  = (const float*)d_in[11];
    const float* adaw  = (const float*)d_in[12];
    const float* adab  = (const float*)d_in[13];
    float* out = (float*)d_out;

    // Workspace layout (peak 48 MB + 48 KB):
    //   [mods 48K][A 8MB][B 8MB][C-slot: vT 8MB, later mid 32MB]
    // d_out (f32, 16.8 MB) doubles as bf16 scratch h -> ob -> h2 (8.4 MB).
    char* ws = (char*)d_ws;
    const size_t MB8 = (size_t)8 * 1024 * 1024;
    float* mods = (float*)ws;                 // 49152 B
    char*  Aslot = ws + 49152;
    char*  Bslot = Aslot + MB8;
    char*  Cslot = Bslot + MB8;

    u16*   h   = (u16*)d_out;      // LN1 out (dead after qkv gemm)
    u16*   qs  = (u16*)Aslot;      // (b,h,s,d)
    u16*   ks  = (u16*)Bslot;      // (b,h,s,d)
    u16*   vT  = (u16*)Cslot;      // (b,h,d,s) (dead after attn)
    u16*   ob  = (u16*)d_out;      // attn out (dead after out-proj)
    float* x2  = (float*)Aslot;    // 16MB f32, overlays dead qs+ks
    u16*   h2  = (u16*)d_out;      // LN2 out (dead after fc1)
    u16*   mid = (u16*)Cslot;      // 32MB, overlays dead vT and beyond

    mods_kernel<<<6144, 64, 0, stream>>>(c, adaw, adab, mods);
    // h = LN(x)*(1+scale_msa)+shift_msa
    ln_mod_kernel<<<4096, 256, 0, stream>>>(x, n1w, mods, 1024, 0, h);
    // qkv = h @ qkv_w^T, scattered to qs/ks/vT (un-roped)
    gemm_kernel<4><<<dim3(48, 64), 256, 0, stream>>>(h, qkvw, 4096, 3072, 1024,
        nullptr, nullptr, nullptr, nullptr, vT, qs, ks);
    rope_qk_kernel<<<16384, 256, 0, stream>>>(qs, ks, rcos, rsin);
    rope_v_kernel<<<8192, 256, 0, stream>>>(vT, rcos, rsin);
    attn_kernel<<<1024, 256, 0, stream>>>(qs, ks, vT, ob);
    // x2 = gate_msa * (o @ out_w^T) + x
    gemm_kernel<2><<<dim3(16, 64), 256, 0, stream>>>(ob, outw, 4096, 1024, 1024,
        mods, nullptr, x, x2, nullptr, nullptr, nullptr);
    // h2 = LN(x2)*(1+scale_mlp)+shift_mlp
    ln_mod_kernel<<<4096, 256, 0, stream>>>(x2, n2w, mods, 4096, 3072, h2);
    // mid = gelu(h2 @ fc1_w^T + fc1_b)
    gemm_kernel<1><<<dim3(64, 64), 256, 0, stream>>>(h2, fc1w, 4096, 4096, 1024,
        nullptr, fc1b, nullptr, nullptr, mid, nullptr, nullptr);
    // out = gate_mlp * (mid @ fc2_w^T + fc2_b) + x2
    gemm_kernel<3><<<dim3(16, 64), 256, 0, stream>>>(mid, fc2w, 4096, 1024, 4096,
        mods, fc2b, x2, out, nullptr, nullptr, nullptr);
}